// Round 2
// baseline (113841.187 us; speedup 1.0000x reference)
//
#include <hip/hip_runtime.h>

#define T_STEPS 1000
#define NI 700
#define NH 4096
#define NO 20

#define ALPHA 0.8187307530779818f   /* exp(-0.2)  synaptic decay */
#define BETA  0.9048374180359595f   /* exp(-0.1)  membrane decay */
#define THRESH 1.0f

#define NBH 64          /* hidden blocks */
#define NPB 64          /* neurons per hidden block */
#define BLOCK 256

/* ---------------- transpose: out[c*R + r] = in[r*C + c] ---------------- */
__global__ void __launch_bounds__(256)
tpose_kernel(const float* __restrict__ in, float* __restrict__ out, int R, int C)
{
    __shared__ float tile[32][33];
    const int c  = blockIdx.x * 32 + threadIdx.x;
    const int r0 = blockIdx.y * 32;
    for (int dy = threadIdx.y; dy < 32; dy += 8) {
        const int r = r0 + dy;
        if (r < R && c < C) tile[dy][threadIdx.x] = in[(size_t)r * C + c];
    }
    __syncthreads();
    const int r2 = r0 + threadIdx.x;
    for (int dy = threadIdx.y; dy < 32; dy += 8) {
        const int c2 = blockIdx.x * 32 + dy;
        if (c2 < C && r2 < R) out[(size_t)c2 * R + r2] = tile[threadIdx.x][dy];
    }
}

/* ---------------- persistent SNN kernel ---------------- */
__global__ void __launch_bounds__(BLOCK)
snn_kernel(const float* __restrict__ inp,     /* [T, NI] */
           const float* __restrict__ W_ro,    /* [NO, NH] row-major */
           const float* __restrict__ W_inT,   /* [NI, NH] */
           const float* __restrict__ W_fbT,   /* [NH, NH] */
           float* __restrict__ out,           /* [NO, T] */
           int* __restrict__ Lbuf,            /* [2][NBH][NPB] spike index segments */
           int* __restrict__ Lcnt,            /* [2][NBH] */
           int* __restrict__ doneA,           /* [T] hidden arrival counters */
           int* __restrict__ doneRO)          /* [T] readout-done flags */
{
    const int tid  = threadIdx.x;
    const int lane = tid & 63;
    const int w    = tid >> 6;
    const int b    = blockIdx.x;

    /* ---------------- readout block ---------------- */
    if (b == NBH) {
        __shared__ int rcnt[NBH];
        float mem2 = 0.f, syn2 = 0.f;
        for (int t = 0; t < T_STEPS; ++t) {
            if (tid == 0) {
                while (__hip_atomic_load(&doneA[t], __ATOMIC_ACQUIRE,
                                         __HIP_MEMORY_SCOPE_AGENT) < NBH)
                    __builtin_amdgcn_s_sleep(2);
            }
            __syncthreads();
            const int p = t & 1;
            if (tid < NBH) rcnt[tid] = Lcnt[p * NBH + tid];
            __syncthreads();
            if (tid < NO) {
                float rc = 0.f;
                for (int bb = 0; bb < NBH; ++bb) {
                    const int c = rcnt[bb];
                    const int* __restrict__ src = &Lbuf[(p * NBH + bb) * NPB];
                    for (int n = 0; n < c; ++n) rc += W_ro[tid * NH + src[n]];
                }
                const float m2n = mem2 * BETA + syn2;
                out[tid * T_STEPS + t] = m2n;
                syn2 = syn2 * ALPHA + rc;
                mem2 = m2n;
            }
            __syncthreads();
            if (tid == 0) {
                __threadfence();
                __hip_atomic_store(&doneRO[t], 1, __ATOMIC_RELEASE,
                                   __HIP_MEMORY_SCOPE_AGENT);
            }
        }
        return;
    }

    /* ---------------- hidden block ---------------- */
    __shared__ int   actI[NI];
    __shared__ int   actH[NH];
    __shared__ float pcur[BLOCK];
    __shared__ int   scnt[NBH], hoff[NBH];
    __shared__ int   wcnt[4], wof[4];
    __shared__ int   actIn, actHn;

    const int i = b * NPB + lane;   /* neuron owned by wave-0 lane; gather col for all waves */
    float mem1 = 0.f, syn1 = 0.f, sflag = 0.f;

    for (int t = 0; t < T_STEPS; ++t) {
        /* readout must be done with the list buffer (parity t&1) we overwrite this step */
        if (t >= 2 && tid == 0) {
            while (__hip_atomic_load(&doneRO[t - 2], __ATOMIC_ACQUIRE,
                                     __HIP_MEMORY_SCOPE_AGENT) == 0)
                __builtin_amdgcn_s_sleep(1);
        }

        /* S0: ballot input-spike row t (wave w handles j in [w*176, w*176+176)) */
        const float* __restrict__ row = inp + (size_t)t * NI;
        unsigned long long m0, m1, m2;
        {
            const int jbase = w * 176;
            const int jend  = min(NI, jbase + 176);
            int j;
            j = jbase + lane;        m0 = __ballot(j < jend && row[j] > 0.5f);
            j = jbase + 64 + lane;   m1 = __ballot(j < jend && row[j] > 0.5f);
            j = jbase + 128 + lane;  m2 = __ballot(j < jend && row[j] > 0.5f);
            if (lane == 0) wcnt[w] = __popcll(m0) + __popcll(m1) + __popcll(m2);
        }
        const int pprev = (t - 1) & 1;
        if (t > 0 && tid < NBH) scnt[tid] = Lcnt[pprev * NBH + tid];
        __syncthreads();

        /* S1: prefix sums (tid 0) */
        if (tid == 0) {
            int off = 0;
            for (int ww = 0; ww < 4; ++ww) { wof[ww] = off; off += wcnt[ww]; }
            actIn = off;
            if (t > 0) {
                int ho = 0;
                for (int bb = 0; bb < NBH; ++bb) { hoff[bb] = ho; ho += scnt[bb]; }
                actHn = ho;
            }
        }
        __syncthreads();

        /* S2: write compacted lists */
        {
            int off = wof[w];
            const int j0 = w * 176 + lane;
            if ((m0 >> lane) & 1) actI[off + __popcll(m0 & ((1ULL << lane) - 1))] = j0;
            off += __popcll(m0);
            if ((m1 >> lane) & 1) actI[off + __popcll(m1 & ((1ULL << lane) - 1))] = j0 + 64;
            off += __popcll(m1);
            if ((m2 >> lane) & 1) actI[off + __popcll(m2 & ((1ULL << lane) - 1))] = j0 + 128;
        }
        if (t > 0 && tid < NBH) {
            const int c = scnt[tid], o = hoff[tid];
            const int* __restrict__ src = &Lbuf[(pprev * NBH + tid) * NPB];
            for (int n = 0; n < c; ++n) actH[o + n] = src[n];
        }
        __syncthreads();

        /* S3: gather columns (K-split across the 4 waves) */
        float acc = 0.f;
        {
            const int nI = actIn;
            #pragma unroll 4
            for (int n = w; n < nI; n += 4) acc += W_inT[actI[n] * NH + i];
            if (t > 0) {
                const int nH = actHn;
                #pragma unroll 4
                for (int n = w; n < nH; n += 4) acc += W_fbT[actH[n] * NH + i];
            }
        }
        pcur[tid] = acc;
        __syncthreads();

        /* S4: neuron update + spike publish (wave 0 owns state) */
        if (w == 0) {
            const float cur = pcur[lane] + pcur[lane + 64] + pcur[lane + 128] + pcur[lane + 192];
            mem1 *= (1.f - sflag);
            const float onew = (mem1 - THRESH > 0.f) ? 1.f : 0.f;
            mem1 = mem1 * BETA + syn1;
            syn1 = syn1 * ALPHA + cur;
            sflag = onew;
            const unsigned long long sm = __ballot(onew > 0.f);
            const int pc = t & 1;
            if (onew > 0.f)
                Lbuf[(pc * NBH + b) * NPB + __popcll(sm & ((1ULL << lane) - 1))] = i;
            if (lane == 0) Lcnt[pc * NBH + b] = __popcll(sm);
        }
        __syncthreads();

        /* S5: device-scope arrival barrier for step t */
        if (tid == 0) {
            __threadfence();
            __hip_atomic_fetch_add(&doneA[t], 1, __ATOMIC_RELEASE,
                                   __HIP_MEMORY_SCOPE_AGENT);
            while (__hip_atomic_load(&doneA[t], __ATOMIC_ACQUIRE,
                                     __HIP_MEMORY_SCOPE_AGENT) < NBH)
                __builtin_amdgcn_s_sleep(1);
        }
        __syncthreads();
    }
}

extern "C" void kernel_launch(void* const* d_in, const int* in_sizes, int n_in,
                              void* d_out, int out_size, void* d_ws, size_t ws_size,
                              hipStream_t stream)
{
    const float* inp  = (const float*)d_in[0];   /* [T, NI]  */
    const float* W_in = (const float*)d_in[1];   /* [NH, NI] */
    const float* W_fb = (const float*)d_in[2];   /* [NH, NH] */
    const float* W_ro = (const float*)d_in[3];   /* [NO, NH] */
    float* out = (float*)d_out;

    char* ws = (char*)d_ws;
    size_t off = 0;
    auto alloc = [&](size_t bytes) -> void* {
        void* p = ws + off;
        off = (off + bytes + 255) & ~(size_t)255;
        return p;
    };
    float* W_fbT  = (float*)alloc(sizeof(float) * (size_t)NH * NH);
    float* W_inT  = (float*)alloc(sizeof(float) * (size_t)NI * NH);
    int*   Lbuf   = (int*)alloc(sizeof(int) * 2 * NBH * NPB);
    int*   Lcnt   = (int*)alloc(sizeof(int) * 2 * NBH);
    int*   doneA  = (int*)alloc(sizeof(int) * T_STEPS);
    int*   doneRO = (int*)alloc(sizeof(int) * T_STEPS);

    hipMemsetAsync(doneA, 0, sizeof(int) * T_STEPS, stream);
    hipMemsetAsync(doneRO, 0, sizeof(int) * T_STEPS, stream);

    dim3 tb(32, 8);
    tpose_kernel<<<dim3((NH + 31) / 32, (NH + 31) / 32), tb, 0, stream>>>(W_fb, W_fbT, NH, NH);
    tpose_kernel<<<dim3((NI + 31) / 32, (NH + 31) / 32), tb, 0, stream>>>(W_in, W_inT, NH, NI);

    snn_kernel<<<NBH + 1, BLOCK, 0, stream>>>(inp, W_ro, W_inT, W_fbT, out,
                                              Lbuf, Lcnt, doneA, doneRO);
}

// Round 3
// 9964.323 us; speedup vs baseline: 11.4249x; 11.4249x over previous
//
#include <hip/hip_runtime.h>

#define T_STEPS 1000
#define NI 700
#define NH 4096
#define NO 20

#define ALPHA 0.8187307530779818f   /* exp(-0.2)  synaptic decay */
#define BETA  0.9048374180359595f   /* exp(-0.1)  membrane decay */

#define NBH 64          /* hidden blocks */
#define NPB 64          /* neurons per hidden block */
#define BLOCK 1024      /* threads per block: 16 waves */
#define NWAVE 16
#define PHASES 4        /* spike-list double^2 buffering */
#define FPAD 16         /* ints per flag slot = 64B, one cacheline per writer */

/* ---------------- transpose: out[c*R + r] = in[r*C + c] ---------------- */
__global__ void __launch_bounds__(256)
tpose_kernel(const float* __restrict__ in, float* __restrict__ out, int R, int C)
{
    __shared__ float tile[32][33];
    const int c  = blockIdx.x * 32 + threadIdx.x;
    const int r0 = blockIdx.y * 32;
    for (int dy = threadIdx.y; dy < 32; dy += 8) {
        const int r = r0 + dy;
        if (r < R && c < C) tile[dy][threadIdx.x] = in[(size_t)r * C + c];
    }
    __syncthreads();
    const int r2 = r0 + threadIdx.x;
    for (int dy = threadIdx.y; dy < 32; dy += 8) {
        const int c2 = blockIdx.x * 32 + dy;
        if (c2 < C && r2 < R) out[(size_t)c2 * R + r2] = tile[threadIdx.x][dy];
    }
}

/* ---------------- persistent SNN kernel ---------------- */
__global__ void __launch_bounds__(BLOCK)
snn_kernel(const float* __restrict__ inp,     /* [T, NI] */
           const float* __restrict__ W_ro,    /* [NO, NH] row-major */
           const float* __restrict__ W_inT,   /* [NI, NH] */
           const float* __restrict__ W_fbT,   /* [NH, NH] */
           float* __restrict__ out,           /* [NO, T] */
           int* __restrict__ Lbuf,            /* [PHASES][NBH][NPB] spike segments */
           int* __restrict__ Lcnt,            /* [PHASES][NBH] */
           int* __restrict__ arrA,            /* [NBH][FPAD] arrival flags (value = steps done) */
           int* __restrict__ roFlag)          /* [FPAD] readout progress flag */
{
    const int tid  = threadIdx.x;
    const int lane = tid & 63;
    const int w    = tid >> 6;
    const int b    = blockIdx.x;

    /* ================= readout block ================= */
    if (b == NBH) {
        __shared__ int rcnt[NBH], roff[NBH];
        __shared__ int actR[NH];
        __shared__ int actRn_s;
        float mem2 = 0.f, syn2 = 0.f;

        for (int t = 0; t < T_STEPS; ++t) {
            /* wait: all hidden blocks published step t (flag value t+1) */
            if (tid < NBH) {
                while (__hip_atomic_load(&arrA[tid * FPAD], __ATOMIC_ACQUIRE,
                                         __HIP_MEMORY_SCOPE_AGENT) < t + 1)
                    __builtin_amdgcn_s_sleep(2);
            }
            __syncthreads();

            const int p = t & (PHASES - 1);
            if (tid < NBH) rcnt[tid] = Lcnt[p * NBH + tid];
            __syncthreads();

            if (w == 0) {   /* 64-wide inclusive shfl scan -> segment offsets */
                int v = rcnt[lane];
                #pragma unroll
                for (int d = 1; d < 64; d <<= 1) {
                    int u = __shfl_up(v, d, 64);
                    if (lane >= d) v += u;
                }
                roff[lane] = v - rcnt[lane];
                if (lane == 63) actRn_s = v;
            }
            __syncthreads();

            {   /* parallel compaction of spike list into LDS */
                const int bb = tid & 63;
                const int c = rcnt[bb], o = roff[bb];
                const int* __restrict__ src = &Lbuf[(p * NBH + bb) * NPB];
                for (int n = tid >> 6; n < c; n += NWAVE) actR[o + n] = src[n];
            }
            __syncthreads();

            const int nR = actRn_s;
            if (tid < NO * 32) {      /* 32 threads per output row */
                const int o = tid >> 5, k = tid & 31;
                float rc = 0.f;
                for (int n = k; n < nR; n += 32) rc += W_ro[o * NH + actR[n]];
                #pragma unroll
                for (int d = 16; d; d >>= 1) rc += __shfl_xor(rc, d, 32);
                if (k == 0) {
                    const float m2n = mem2 * BETA + syn2;
                    out[o * T_STEPS + t] = m2n;
                    syn2 = syn2 * ALPHA + rc;
                    mem2 = m2n;
                }
            }
            __syncthreads();    /* compiler drains vmcnt before barrier -> Lbuf reads done */
            if (tid == 0) {
                __threadfence();
                __hip_atomic_store(&roFlag[0], t + 1, __ATOMIC_RELEASE,
                                   __HIP_MEMORY_SCOPE_AGENT);
            }
        }
        return;
    }

    /* ================= hidden block ================= */
    __shared__ int   actI[NI + 4];
    __shared__ int   actH[NH];
    __shared__ float pcur[BLOCK];
    __shared__ int   scnt[NBH], hoff[NBH];
    __shared__ int   wcnt[NWAVE], wof[NWAVE];
    __shared__ int   actIn_s, actHn_s;

    const int i = b * NPB + lane;            /* this block's neuron slice column */
    const int CHUNK = (NI + NWAVE - 1) / NWAVE;   /* 44 inputs per wave */
    float mem1 = 0.f, syn1 = 0.f, sflag = 0.f;

    for (int t = 0; t < T_STEPS; ++t) {
        /* W1: all hidden blocks finished step t-1 (flag >= t). one lane per flag line */
        if (t > 0 && tid < NBH) {
            while (__hip_atomic_load(&arrA[tid * FPAD], __ATOMIC_ACQUIRE,
                                     __HIP_MEMORY_SCOPE_AGENT) < t)
                __builtin_amdgcn_s_sleep(2);
        }
        /* W2: readout consumed the phase we are about to overwrite (step t-4) */
        if (t >= PHASES && tid == NBH) {
            while (__hip_atomic_load(&roFlag[0], __ATOMIC_ACQUIRE,
                                     __HIP_MEMORY_SCOPE_AGENT) < t - (PHASES - 1))
                __builtin_amdgcn_s_sleep(2);
        }
        __syncthreads();

        /* S0: ballot input-spike row t; load prev-step spike counts */
        const float* __restrict__ row = inp + (size_t)t * NI;
        const int jbase = w * CHUNK;
        const int jend  = min(NI, jbase + CHUNK);
        const int j     = jbase + lane;
        const unsigned long long m = __ballot(j < jend && row[j] > 0.5f);
        if (lane == 0) wcnt[w] = __popcll(m);
        const int pprev = (t - 1) & (PHASES - 1);
        if (t > 0 && tid < NBH) scnt[tid] = Lcnt[pprev * NBH + tid];
        __syncthreads();

        /* S1: wave-parallel scans */
        if (w == 0) {
            if (t > 0) {
                int v = scnt[lane];
                #pragma unroll
                for (int d = 1; d < 64; d <<= 1) {
                    int u = __shfl_up(v, d, 64);
                    if (lane >= d) v += u;
                }
                hoff[lane] = v - scnt[lane];
                if (lane == 63) actHn_s = v;
            }
            if (lane == 0) {
                int off = 0;
                #pragma unroll
                for (int ww = 0; ww < NWAVE; ++ww) { wof[ww] = off; off += wcnt[ww]; }
                actIn_s = off;
            }
        }
        __syncthreads();

        /* S2: compacted lists (input indices; prev-step hidden spike indices) */
        if ((m >> lane) & 1)
            actI[wof[w] + __popcll(m & ((1ULL << lane) - 1))] = j;
        if (t > 0) {
            const int bb = tid & 63;
            const int c = scnt[bb], o = hoff[bb];
            const int* __restrict__ src = &Lbuf[(pprev * NBH + bb) * NPB];
            for (int n = tid >> 6; n < c; n += NWAVE) actH[o + n] = src[n];
        }
        __syncthreads();

        /* S3: gather active weight columns, 16-way K-split across waves */
        float acc = 0.f;
        {
            const int nI = actIn_s;
            #pragma unroll 4
            for (int n = w; n < nI; n += NWAVE) acc += W_inT[actI[n] * NH + i];
            if (t > 0) {
                const int nH = actHn_s;
                #pragma unroll 4
                for (int n = w; n < nH; n += NWAVE) acc += W_fbT[actH[n] * NH + i];
            }
        }
        pcur[tid] = acc;
        __syncthreads();

        /* S4: LIF update + spike publish (wave 0 owns the 64 neurons) */
        if (w == 0) {
            float cur = 0.f;
            #pragma unroll
            for (int ww = 0; ww < NWAVE; ++ww) cur += pcur[lane + 64 * ww];
            mem1 *= (1.f - sflag);
            const float onew = (mem1 - 1.0f > 0.f) ? 1.f : 0.f;
            mem1 = mem1 * BETA + syn1;
            syn1 = syn1 * ALPHA + cur;
            sflag = onew;
            const unsigned long long sm = __ballot(onew > 0.f);
            const int pc = t & (PHASES - 1);
            if (onew > 0.f)
                Lbuf[(pc * NBH + b) * NPB + __popcll(sm & ((1ULL << lane) - 1))] = i;
            if (lane == 0) Lcnt[pc * NBH + b] = __popcll(sm);
        }
        __syncthreads();    /* drains wave-0 stores before the release below */

        /* arrival: single padded cacheline per block, plain release store */
        if (tid == 0) {
            __threadfence();
            __hip_atomic_store(&arrA[b * FPAD], t + 1, __ATOMIC_RELEASE,
                               __HIP_MEMORY_SCOPE_AGENT);
        }
    }
}

extern "C" void kernel_launch(void* const* d_in, const int* in_sizes, int n_in,
                              void* d_out, int out_size, void* d_ws, size_t ws_size,
                              hipStream_t stream)
{
    const float* inp  = (const float*)d_in[0];   /* [T, NI]  */
    const float* W_in = (const float*)d_in[1];   /* [NH, NI] */
    const float* W_fb = (const float*)d_in[2];   /* [NH, NH] */
    const float* W_ro = (const float*)d_in[3];   /* [NO, NH] */
    float* out = (float*)d_out;

    char* ws = (char*)d_ws;
    size_t off = 0;
    auto alloc = [&](size_t bytes) -> void* {
        void* p = ws + off;
        off = (off + bytes + 255) & ~(size_t)255;
        return p;
    };
    float* W_fbT  = (float*)alloc(sizeof(float) * (size_t)NH * NH);
    float* W_inT  = (float*)alloc(sizeof(float) * (size_t)NI * NH);
    int*   Lbuf   = (int*)alloc(sizeof(int) * PHASES * NBH * NPB);
    int*   Lcnt   = (int*)alloc(sizeof(int) * PHASES * NBH);
    int*   arrA   = (int*)alloc(sizeof(int) * NBH * FPAD);
    int*   roFlag = (int*)alloc(sizeof(int) * FPAD);

    hipMemsetAsync(arrA, 0, sizeof(int) * NBH * FPAD, stream);
    hipMemsetAsync(roFlag, 0, sizeof(int) * FPAD, stream);

    dim3 tb(32, 8);
    tpose_kernel<<<dim3((NH + 31) / 32, (NH + 31) / 32), tb, 0, stream>>>(W_fb, W_fbT, NH, NH);
    tpose_kernel<<<dim3((NI + 31) / 32, (NH + 31) / 32), tb, 0, stream>>>(W_in, W_inT, NH, NI);

    snn_kernel<<<NBH + 1, BLOCK, 0, stream>>>(inp, W_ro, W_inT, W_fbT, out,
                                              Lbuf, Lcnt, arrA, roFlag);
}